// Round 3
// baseline (3448.677 us; speedup 1.0000x reference)
//
#include <hip/hip_runtime.h>
#include <math.h>

// SSIM via fully separable pipeline, u/v-reformulated, software-pipelined,
// FORCE-UNROLLED. img1,img2: [32,3,512,512] fp32 -> scalar mean.
//
// Round-5 fix: round 4 (same algorithm, pragma-unrolled) spilled the
// accumulator ring to scratch (WRITE_SIZE 99MB->4.4GB, VALUBusy 84%->3.5%,
// 10x slower). Cause: the 11-iteration pair loop (contains __syncthreads)
// crossed the compiler's full-unroll threshold; with jj runtime the ring
// phase ph=(2jj+e)%11 became runtime -> acc[se] runtime-indexed -> rule #20
// demotion to local memory. Fix: expand the 11 pair-steps via macros with
// LITERAL JJ so every ring/weight/acc index is a constant expression
// independent of unroll heuristics.
//
// Algorithm (round 4, kept): SSIM needs only 4 convolutions, not 6:
//   u = x+y, v = x-y;  U=E[u], V=E[v], P=E[u^2], Q=E[v^2]
//   mu1*mu2      = (U^2-V^2)/4      mu1^2+mu2^2   = (U^2+V^2)/2
//   E[xy]        = (P-Q)/4          E[x^2]+E[y^2] = (P+Q)/2
// Planes {u,v,u^2,v^2} staged in LDS (squares computed once per input
// pixel at commit), h-conv = 4 fma/tap, v-conv ring = 4x11. IEEE divide
// replaced by v_rcp + 1 Newton step.
//
// Kept from round 3 (T14, verified 272->181us): loads for rows r+2,r+3
// ISSUED into registers right after the barrier, 2 rows of conv math run,
// then registers are COMMITTED to LDS. 2 rows/barrier, 4-row LDS ring.
//
// Round-2 lesson: __launch_bounds__(256,4) (128-VGPR cap) forced the ring
// into scratch. Cap at 256 VGPRs instead.

#define IH 512
#define IW 512
#define NCH 96            // 32*3 depthwise channels
#define TW 256            // tile width == blockDim.x
#define TH 34             // output rows per block
#define SSTR 272          // LDS row stride (266 used)
#define TYB 16            // ceil(512/34) block-rows
#define C1f (0.01f * 0.01f)
#define C2f (0.03f * 0.03f)

struct Weights { float w[11]; };

// ---- one output row: h-conv from LDS, ring scatter, emit. PH is a LITERAL
//      constant expression -> all ring/weight/acc indices constant-fold. ----
#define ROW_STEP(RR, PH) do {                                           \
    const int r_  = (RR);                                               \
    const int p_  = r_ & 3;                                             \
    const float* __restrict__ rowU_ = &sU [p_][tid];                    \
    const float* __restrict__ rowV_ = &sV [p_][tid];                    \
    const float* __restrict__ rowP_ = &sUU[p_][tid];                    \
    const float* __restrict__ rowQ_ = &sVV[p_][tid];                    \
    float hu_ = 0.f, hv_ = 0.f, hp_ = 0.f, hq_ = 0.f;                   \
    _Pragma("unroll")                                                   \
    for (int k = 0; k < 11; ++k) {                                      \
        const float wk_ = wt.w[k];                                      \
        hu_ = fmaf(wk_, rowU_[k], hu_);                                 \
        hv_ = fmaf(wk_, rowV_[k], hv_);                                 \
        hp_ = fmaf(wk_, rowP_[k], hp_);                                 \
        hq_ = fmaf(wk_, rowQ_[k], hq_);                                 \
    }                                                                   \
    _Pragma("unroll")                                                   \
    for (int s = 0; s < 11; ++s) {                                      \
        const int wi_ = ((PH) - s + 11) % 11;  /* constant-folds */     \
        const float wk_ = wt.w[wi_];                                    \
        if (wi_ == 0) {        /* first tap of window: assign */        \
            accU[s] = wk_ * hu_;  accV[s] = wk_ * hv_;                  \
            accP[s] = wk_ * hp_;  accQ[s] = wk_ * hq_;                  \
        } else {                                                        \
            accU[s] = fmaf(wk_, hu_, accU[s]);                          \
            accV[s] = fmaf(wk_, hv_, accV[s]);                          \
            accP[s] = fmaf(wk_, hp_, accP[s]);                          \
            accQ[s] = fmaf(wk_, hq_, accQ[s]);                          \
        }                                                               \
    }                                                                   \
    {                                                                   \
        const int se_ = ((PH) + 1) % 11;       /* constant-folds */     \
        const float Uo_ = accU[se_], Vo_ = accV[se_];                   \
        const float Po_ = accP[se_], Qo_ = accQ[se_];                   \
        const float A_   = Uo_ * Uo_;                                   \
        const float B_   = Vo_ * Vo_;                                   \
        const float ApB_ = A_ + B_;                                     \
        const float AmB_ = A_ - B_;                                     \
        const float PpQ_ = Po_ + Qo_;                                   \
        const float PmQ_ = Po_ - Qo_;                                   \
        const float numl_ = fmaf(0.5f, AmB_, C1f);                      \
        const float numr_ = fmaf(0.5f, PmQ_ - AmB_, C2f);               \
        const float denl_ = fmaf(0.5f, ApB_, C1f);                      \
        const float denr_ = fmaf(0.5f, PpQ_ - ApB_, C2f);               \
        const float num_ = numl_ * numr_;                               \
        const float den_ = denl_ * denr_;                               \
        float rc_ = __builtin_amdgcn_rcpf(den_);                        \
        rc_ = rc_ * fmaf(-den_, rc_, 2.0f);   /* 1 Newton step */       \
        const int o_ = r_ - 10;                                         \
        const bool valid_ = (o_ >= 0) && (row_out0 + o_ < IH);          \
        tsum += valid_ ? (num_ * rc_) : 0.f;                            \
    }                                                                   \
} while (0)

// ---- one pair: barrier, issue prefetch, 2 row steps, commit prefetch ----
#define PAIR_STEP(JJ) do {                                              \
    const int rp_ = gbase + 2 * (JJ);                                   \
    __syncthreads();                                                    \
    const bool more_ = (rp_ + 2) < 44;     /* wave-uniform */           \
    if (more_) {                                                        \
        issue(rp_ + 2, pa0, pb0, pa1, pb1);                             \
        issue(rp_ + 3, qa0, qb0, qa1, qb1);                             \
    }                                                                   \
    ROW_STEP(rp_,     ((2 * (JJ))     % 11));                           \
    ROW_STEP(rp_ + 1, ((2 * (JJ) + 1) % 11));                           \
    if (more_) {                                                        \
        commit(rp_ + 2, pa0, pb0, pa1, pb1);                            \
        commit(rp_ + 3, qa0, qb0, qa1, qb1);                            \
    }                                                                   \
} while (0)

__global__ __launch_bounds__(256, 2) void ssim_kernel(
    const float* __restrict__ img1, const float* __restrict__ img2,
    float* __restrict__ partial, Weights wt)
{
    __shared__ float sU [4][SSTR];   // 4-row ring, buffer = row & 3
    __shared__ float sV [4][SSTR];
    __shared__ float sUU[4][SSTR];
    __shared__ float sVV[4][SSTR];
    __shared__ float wave_sums[4];

    const int tid = threadIdx.x;
    const int bx  = blockIdx.x;
    const int tx  = bx & 1;          // 2 col tiles
    const int ty  = (bx >> 1) & 15;  // 16 row tiles
    const int ch  = bx >> 5;         // 96 channels

    const int col0     = tx * TW;
    const int row_out0 = ty * TH;
    const int row0     = row_out0 - 5;       // staging row r -> global row row0+r
    const size_t choff = (size_t)ch * IH * IW;

    // column halo indices (fixed per thread)
    const int  gc0   = col0 - 5 + tid;
    const bool colv0 = ((unsigned)gc0 < (unsigned)IW);
    const int  gc1   = gc0 + TW;                   // staged by tid < 10
    const bool colv1 = ((unsigned)gc1 < (unsigned)IW);
    const bool halo  = (tid < 10);

    // two register staging slots (fixed names -> no runtime reg indexing)
    float pa0, pb0, pa1, pb1;        // slot P: even row of the pair
    float qa0, qb0, qa1, qb1;        // slot Q: odd row of the pair

    auto issue = [&](int r, float& a0, float& b0, float& a1, float& b1) {
        const int gr = row0 + r;                   // wave-uniform
        const bool rowv = ((unsigned)gr < (unsigned)IH);
        const long rowoff = (long)choff + (long)gr * IW;
        a0 = 0.f; b0 = 0.f; a1 = 0.f; b1 = 0.f;
        if (rowv & colv0) {
            a0 = img1[rowoff + gc0];
            b0 = img2[rowoff + gc0];
        }
        if (rowv & colv1 & halo) {
            a1 = img1[rowoff + gc1];
            b1 = img2[rowoff + gc1];
        }
    };
    // commit: compute u,v,u^2,v^2 ONCE per staged pixel, write 4 planes.
    auto commit = [&](int r, float a0, float b0, float a1, float b1) {
        const int p = r & 3;
        const float u0 = a0 + b0, v0 = a0 - b0;
        sU [p][tid] = u0;
        sV [p][tid] = v0;
        sUU[p][tid] = u0 * u0;
        sVV[p][tid] = v0 * v0;
        if (halo) {
            const float u1 = a1 + b1, v1 = a1 - b1;
            sU [p][tid + TW] = u1;
            sV [p][tid + TW] = v1;
            sUU[p][tid + TW] = u1 * u1;
            sVV[p][tid + TW] = v1 * v1;
        }
    };

    // accumulator ring: slot s holds output row o with o % 11 == s.
    // Zero-init only to avoid reading junk in the (discarded) warm-up emits.
    float accU[11], accV[11], accP[11], accQ[11];
    #pragma unroll
    for (int s = 0; s < 11; ++s)
        accU[s] = accV[s] = accP[s] = accQ[s] = 0.f;

    float tsum = 0.f;

    // prologue: rows 0,1 staged (one-time full-latency wait)
    issue(0, pa0, pb0, pa1, pb1);
    issue(1, qa0, qb0, qa1, qb1);
    commit(0, pa0, pb0, pa1, pb1);
    commit(1, qa0, qb0, qa1, qb1);

    for (int g = 0; g < 2; ++g) {
        const int gbase = g * 22;    // pair period 22 == 0 mod 11
        PAIR_STEP(0);  PAIR_STEP(1);  PAIR_STEP(2);  PAIR_STEP(3);
        PAIR_STEP(4);  PAIR_STEP(5);  PAIR_STEP(6);  PAIR_STEP(7);
        PAIR_STEP(8);  PAIR_STEP(9);  PAIR_STEP(10);
    }

    // ---- block reduction ----
    #pragma unroll
    for (int off = 32; off > 0; off >>= 1)
        tsum += __shfl_down(tsum, off);
    if ((tid & 63) == 0) wave_sums[tid >> 6] = tsum;
    __syncthreads();
    if (tid == 0) {
        partial[blockIdx.x] =
            wave_sums[0] + wave_sums[1] + wave_sums[2] + wave_sums[3];
    }
}

__global__ __launch_bounds__(256) void reduce_kernel(
    const float* __restrict__ partial, int n, float* __restrict__ out,
    double inv_count)
{
    __shared__ double wave_sums[4];
    const int tid = threadIdx.x;
    double s = 0.0;
    for (int i = tid; i < n; i += 256) s += (double)partial[i];
    #pragma unroll
    for (int off = 32; off > 0; off >>= 1)
        s += __shfl_down(s, off);
    if ((tid & 63) == 0) wave_sums[tid >> 6] = s;
    __syncthreads();
    if (tid == 0) {
        out[0] = (float)((wave_sums[0] + wave_sums[1] +
                          wave_sums[2] + wave_sums[3]) * inv_count);
    }
}

extern "C" void kernel_launch(void* const* d_in, const int* in_sizes, int n_in,
                              void* d_out, int out_size, void* d_ws, size_t ws_size,
                              hipStream_t stream)
{
    const float* img1 = (const float*)d_in[0];
    const float* img2 = (const float*)d_in[1];
    float* out = (float*)d_out;
    float* partial = (float*)d_ws;   // 3072 floats = 12 KB scratch

    // Gaussian window (ws=11, sigma=1.5) in fp32, matching the reference
    Weights wt;
    {
        float s = 0.f;
        for (int i = 0; i < 11; ++i) {
            const float d = (float)(i - 5);
            wt.w[i] = expf(-(d * d) / 4.5f);
            s += wt.w[i];
        }
        for (int i = 0; i < 11; ++i) wt.w[i] /= s;
    }

    const int nblocks = NCH * TYB * 2;   // 3072

    ssim_kernel<<<nblocks, 256, 0, stream>>>(img1, img2, partial, wt);

    const double inv_count = 1.0 / ((double)NCH * IH * IW);
    reduce_kernel<<<1, 256, 0, stream>>>(partial, nblocks, out, inv_count);
}

// Round 4
// 320.712 us; speedup vs baseline: 10.7532x; 10.7532x over previous
//
#include <hip/hip_runtime.h>
#include <math.h>

// SSIM via fully separable pipeline, u/v-reformulated (2-plane form),
// software-pipelined. img1,img2: [32,3,512,512] fp32 -> scalar mean.
//
// Round-6: rounds 4/5 (4-LDS-plane u/v variant) hit an effective 128-VGPR
// allocator ceiling (VGPR_Count pinned at exactly 128, acc ring evicted to
// scratch: WRITE_SIZE 99MB->5GB, VALUBusy 84%->3.4%, 18x slower) REGARDLESS
// of index constness (round 5 force-unrolled every acc index to a literal
// and still spilled). Lesson: don't fight the allocator -- shrink footprint.
// This round: revert to the proven round-3 structure (84 VGPR, 181us, same
// loop shape / contraction spelling / IEEE divide) and apply u/v in 2-plane
// form, which REDUCES register demand vs that kernel (ring 55->44 regs):
//   u = x+y, v = x-y;  U=E[u], V=E[v], P=E[u^2], Q=E[v^2]
//   mu1*mu2      = (U^2-V^2)/4      mu1^2+mu2^2   = (U^2+V^2)/2
//   E[xy]        = (P-Q)/4          E[x^2]+E[y^2] = (P+Q)/2
// LDS stages only {u,v} (2 planes, same 9216B as round 3); squares are
// computed inline in the h-conv (6 ops/tap over 4 quantities vs 7 ops/tap
// over 5). Per-output VALU ~154 -> ~132.
//
// Kept (T14, verified 272->181us): loads for rows r+2,r+3 ISSUED into
// registers right after the barrier, 2 rows of conv math run, then
// registers are COMMITTED to LDS. 2 rows/barrier, 4-row LDS ring.
// ring phase r%11 compile-time (pair period 22 == 0 mod 11).
//
// Round-2 lesson: __launch_bounds__(256,4) (128-VGPR cap) forced the ring
// into scratch. Cap at 256 VGPRs instead.

#define IH 512
#define IW 512
#define NCH 96            // 32*3 depthwise channels
#define TW 256            // tile width == blockDim.x
#define TH 34             // output rows per block
#define SSTR 272          // LDS row stride (266 used)
#define TYB 16            // ceil(512/34) block-rows
#define C1f (0.01f * 0.01f)
#define C2f (0.03f * 0.03f)

struct Weights { float w[11]; };

__global__ __launch_bounds__(256, 2) void ssim_kernel(
    const float* __restrict__ img1, const float* __restrict__ img2,
    float* __restrict__ partial, Weights wt)
{
    __shared__ float sU[4][SSTR];   // u = x+y; 4-row ring, buffer = row & 3
    __shared__ float sV[4][SSTR];   // v = x-y
    __shared__ float wave_sums[4];

    const int tid = threadIdx.x;
    const int bx  = blockIdx.x;
    const int tx  = bx & 1;          // 2 col tiles
    const int ty  = (bx >> 1) & 15;  // 16 row tiles
    const int ch  = bx >> 5;         // 96 channels

    const int col0     = tx * TW;
    const int row_out0 = ty * TH;
    const int row0     = row_out0 - 5;       // staging row r -> global row row0+r
    const size_t choff = (size_t)ch * IH * IW;

    // column halo indices (fixed per thread)
    const int  gc0   = col0 - 5 + tid;
    const bool colv0 = ((unsigned)gc0 < (unsigned)IW);
    const int  gc1   = gc0 + TW;                   // staged by tid < 10
    const bool colv1 = ((unsigned)gc1 < (unsigned)IW);
    const bool halo  = (tid < 10);

    // two register staging slots (fixed names -> no runtime reg indexing)
    float pa0, pb0, pa1, pb1;        // slot P: even row of the pair
    float qa0, qb0, qa1, qb1;        // slot Q: odd row of the pair

    auto issue = [&](int r, float& a0, float& b0, float& a1, float& b1) {
        const int gr = row0 + r;                   // wave-uniform
        const bool rowv = ((unsigned)gr < (unsigned)IH);
        const long rowoff = (long)choff + (long)gr * IW;
        a0 = 0.f; b0 = 0.f; a1 = 0.f; b1 = 0.f;
        if (rowv & colv0) {
            a0 = img1[rowoff + gc0];
            b0 = img2[rowoff + gc0];
        }
        if (rowv & colv1 & halo) {
            a1 = img1[rowoff + gc1];
            b1 = img2[rowoff + gc1];
        }
    };
    // commit: write u=a+b, v=a-b (2 planes; squares computed in h-conv)
    auto commit = [&](int r, float a0, float b0, float a1, float b1) {
        const int p = r & 3;
        sU[p][tid] = a0 + b0;
        sV[p][tid] = a0 - b0;
        if (halo) {
            sU[p][tid + TW] = a1 + b1;
            sV[p][tid + TW] = a1 - b1;
        }
    };

    // accumulator ring: slot s holds output row o with o % 11 == s.
    // Zero-init only to avoid reading junk in the (discarded) warm-up emits.
    float accU[11], accV[11], accP[11], accQ[11];
    #pragma unroll
    for (int s = 0; s < 11; ++s)
        accU[s] = accV[s] = accP[s] = accQ[s] = 0.f;

    float tsum = 0.f;

    // prologue: rows 0,1 staged (one-time full-latency wait)
    issue(0, pa0, pb0, pa1, pb1);
    issue(1, qa0, qb0, qa1, qb1);
    commit(0, pa0, pb0, pa1, pb1);
    commit(1, qa0, qb0, qa1, qb1);

    for (int g = 0; g < 2; ++g) {
        #pragma unroll
        for (int jj = 0; jj < 11; ++jj) {
            const int rp = g * 22 + jj * 2;   // this pair computes rows rp, rp+1
            __syncthreads();                  // prev commits visible; prev reads done

            const bool more = (rp + 2) < 44;  // wave-uniform
            if (more) {
                issue(rp + 2, pa0, pb0, pa1, pb1);
                issue(rp + 3, qa0, qb0, qa1, qb1);
            }

            #pragma unroll
            for (int e = 0; e < 2; ++e) {
                const int r  = rp + e;
                const int ph = (2 * jj + e) % 11;   // == r % 11, compile-time
                const int p  = r & 3;               // LDS ring buffer (runtime ok)

                // ---- horizontal 11-tap conv: u,v from LDS, squares inline ----
                const float* __restrict__ rowU = &sU[p][tid];
                const float* __restrict__ rowV = &sV[p][tid];
                float hu = 0.f, hv = 0.f, hp = 0.f, hq = 0.f;
                #pragma unroll
                for (int k = 0; k < 11; ++k) {
                    const float u  = rowU[k];
                    const float v  = rowV[k];
                    const float wk = wt.w[k];
                    const float tu = wk * u;
                    const float tv = wk * v;
                    hu += tu;
                    hv += tv;
                    hp += tu * u;
                    hq += tv * v;
                }

                // ---- vertical conv: scatter into ring, weight idx (ph-s) mod 11.
                //      wi==0 is the first tap of the slot's window -> assign. ----
                #pragma unroll
                for (int s = 0; s < 11; ++s) {
                    const int wi = (ph - s + 11) % 11;   // compile-time
                    const float wk = wt.w[wi];
                    if (wi == 0) {
                        accU[s] = wk * hu;
                        accV[s] = wk * hv;
                        accP[s] = wk * hp;
                        accQ[s] = wk * hq;
                    } else {
                        accU[s] += wk * hu;
                        accV[s] += wk * hv;
                        accP[s] += wk * hp;
                        accQ[s] += wk * hq;
                    }
                }

                // ---- emit output row o = r-10 (slot (ph+1)%11) ----
                const int se = (ph + 1) % 11;           // compile-time
                const float Uo = accU[se], Vo = accV[se];
                const float Po = accP[se], Qo = accQ[se];

                const float A   = Uo * Uo;              // U^2
                const float B   = Vo * Vo;              // V^2
                const float ApB = A + B;
                const float AmB = A - B;
                const float PpQ = Po + Qo;
                const float PmQ = Po - Qo;
                // num = (2*mu12 + C1) * (2*sigma12 + C2)
                const float num = (0.5f * AmB + C1f) *
                                  (0.5f * (PmQ - AmB) + C2f);
                // den = (mu1^2+mu2^2 + C1) * (sigma1^2+sigma2^2 + C2)
                const float den = (0.5f * ApB + C1f) *
                                  (0.5f * (PpQ - ApB) + C2f);

                const int o = r - 10;
                const bool valid = (o >= 0) && (row_out0 + o < IH);
                tsum += valid ? (num / den) : 0.f;
            }

            // ---- commit the prefetched pair: vmcnt wait covered by the
            //      conv math above. Loads never cross the barrier. ----
            if (more) {
                commit(rp + 2, pa0, pb0, pa1, pb1);
                commit(rp + 3, qa0, qb0, qa1, qb1);
            }
        }
    }

    // ---- block reduction ----
    #pragma unroll
    for (int off = 32; off > 0; off >>= 1)
        tsum += __shfl_down(tsum, off);
    if ((tid & 63) == 0) wave_sums[tid >> 6] = tsum;
    __syncthreads();
    if (tid == 0) {
        partial[blockIdx.x] =
            wave_sums[0] + wave_sums[1] + wave_sums[2] + wave_sums[3];
    }
}

__global__ __launch_bounds__(256) void reduce_kernel(
    const float* __restrict__ partial, int n, float* __restrict__ out,
    double inv_count)
{
    __shared__ double wave_sums[4];
    const int tid = threadIdx.x;
    double s = 0.0;
    for (int i = tid; i < n; i += 256) s += (double)partial[i];
    #pragma unroll
    for (int off = 32; off > 0; off >>= 1)
        s += __shfl_down(s, off);
    if ((tid & 63) == 0) wave_sums[tid >> 6] = s;
    __syncthreads();
    if (tid == 0) {
        out[0] = (float)((wave_sums[0] + wave_sums[1] +
                          wave_sums[2] + wave_sums[3]) * inv_count);
    }
}

extern "C" void kernel_launch(void* const* d_in, const int* in_sizes, int n_in,
                              void* d_out, int out_size, void* d_ws, size_t ws_size,
                              hipStream_t stream)
{
    const float* img1 = (const float*)d_in[0];
    const float* img2 = (const float*)d_in[1];
    float* out = (float*)d_out;
    float* partial = (float*)d_ws;   // 3072 floats = 12 KB scratch

    // Gaussian window (ws=11, sigma=1.5) in fp32, matching the reference
    Weights wt;
    {
        float s = 0.f;
        for (int i = 0; i < 11; ++i) {
            const float d = (float)(i - 5);
            wt.w[i] = expf(-(d * d) / 4.5f);
            s += wt.w[i];
        }
        for (int i = 0; i < 11; ++i) wt.w[i] /= s;
    }

    const int nblocks = NCH * TYB * 2;   // 3072

    ssim_kernel<<<nblocks, 256, 0, stream>>>(img1, img2, partial, wt);

    const double inv_count = 1.0 / ((double)NCH * IH * IW);
    reduce_kernel<<<1, 256, 0, stream>>>(partial, nblocks, out, inv_count);
}